// Round 1
// baseline (942.594 us; speedup 1.0000x reference)
//
#include <hip/hip_runtime.h>

// Problem: y[b,co,h,w] = sum_ci x[b,ci,h,w] * W[ci,co] + bias[co] at active
// voxels (any channel != 0), else 0.  B=8, CIN=32, COUT=64, H=W=512.
// Memory-bound: 256 MiB read + 512 MiB write -> ~128 us floor at 6.3 TB/s.

#define HW_SHIFT 18          // H*W = 512*512 = 2^18
#define HW_ (1 << HW_SHIFT)
#define CIN 32
#define COUT 64

// Each thread: 4 contiguous spatial positions (float4), all 32 input channels
// held in VGPRs (128 regs), cout blocked by 4; W staged in LDS and read as
// wave-uniform float4 (ds_read_b128 broadcast, conflict-free).
// __launch_bounds__(256,2): cap VGPR at 256 so the 128-reg x cache fits
// without spill (default 1024-thread assumption would force <=128 VGPRs).
__global__ __launch_bounds__(256, 2) void spconv1x1_kernel(
    const float* __restrict__ x, const float* __restrict__ Wm,
    const float* __restrict__ bias, float* __restrict__ out)
{
    __shared__ float sW[CIN * COUT];
    __shared__ float sb[COUT];
    for (int i = threadIdx.x; i < CIN * COUT; i += 256) sW[i] = Wm[i];
    if (threadIdx.x < COUT) sb[threadIdx.x] = bias[threadIdx.x];
    __syncthreads();

    const long tid = (long)blockIdx.x * 256 + threadIdx.x;
    const long p0  = tid * 4;                       // first spatial position
    const int  bidx = (int)(p0 >> HW_SHIFT);        // batch index
    const int  sp   = (int)(p0 & (HW_ - 1));        // position within H*W
    // 4 positions of one thread never straddle a batch (HW divisible by 4).

    const float* xb = x + (((long)bidx * CIN) << HW_SHIFT) + sp;

    // Load all 32 input channels for the 4 positions: 32 independent
    // global_load_dwordx4, coalesced across the wave (1 KiB/instr).
    float4 xv[CIN];
#pragma unroll
    for (int ci = 0; ci < CIN; ci++) {
        xv[ci] = *(const float4*)(xb + ((long)ci << HW_SHIFT));
    }

    // Active mask per position: any channel != 0 (exact reference semantics).
    int a0 = 0, a1 = 0, a2 = 0, a3 = 0;
#pragma unroll
    for (int ci = 0; ci < CIN; ci++) {
        a0 |= (xv[ci].x != 0.0f);
        a1 |= (xv[ci].y != 0.0f);
        a2 |= (xv[ci].z != 0.0f);
        a3 |= (xv[ci].w != 0.0f);
    }

    float* ob = out + (((long)bidx * COUT) << HW_SHIFT) + sp;

    // cout in blocks of 4: 16 accumulator regs, 1 ds_read_b128 per 16 FMAs.
    for (int co = 0; co < COUT; co += 4) {
        float4 acc0 = {0.f, 0.f, 0.f, 0.f};   // cout=co,   positions 0..3
        float4 acc1 = {0.f, 0.f, 0.f, 0.f};   // cout=co+1
        float4 acc2 = {0.f, 0.f, 0.f, 0.f};   // cout=co+2
        float4 acc3 = {0.f, 0.f, 0.f, 0.f};   // cout=co+3
#pragma unroll
        for (int ci = 0; ci < CIN; ci++) {
            const float4 w = *(const float4*)&sW[ci * COUT + co];
            acc0.x += xv[ci].x * w.x; acc0.y += xv[ci].y * w.x;
            acc0.z += xv[ci].z * w.x; acc0.w += xv[ci].w * w.x;
            acc1.x += xv[ci].x * w.y; acc1.y += xv[ci].y * w.y;
            acc1.z += xv[ci].z * w.y; acc1.w += xv[ci].w * w.y;
            acc2.x += xv[ci].x * w.z; acc2.y += xv[ci].y * w.z;
            acc2.z += xv[ci].z * w.z; acc2.w += xv[ci].w * w.z;
            acc3.x += xv[ci].x * w.w; acc3.y += xv[ci].y * w.w;
            acc3.z += xv[ci].z * w.w; acc3.w += xv[ci].w * w.w;
        }

        const float b0 = sb[co], b1 = sb[co + 1], b2 = sb[co + 2], b3 = sb[co + 3];
        float4 r0, r1, r2, r3;
        r0.x = a0 ? acc0.x + b0 : 0.f;  r0.y = a1 ? acc0.y + b0 : 0.f;
        r0.z = a2 ? acc0.z + b0 : 0.f;  r0.w = a3 ? acc0.w + b0 : 0.f;
        r1.x = a0 ? acc1.x + b1 : 0.f;  r1.y = a1 ? acc1.y + b1 : 0.f;
        r1.z = a2 ? acc1.z + b1 : 0.f;  r1.w = a3 ? acc1.w + b1 : 0.f;
        r2.x = a0 ? acc2.x + b2 : 0.f;  r2.y = a1 ? acc2.y + b2 : 0.f;
        r2.z = a2 ? acc2.z + b2 : 0.f;  r2.w = a3 ? acc2.w + b2 : 0.f;
        r3.x = a0 ? acc3.x + b3 : 0.f;  r3.y = a1 ? acc3.y + b3 : 0.f;
        r3.z = a2 ? acc3.z + b3 : 0.f;  r3.w = a3 ? acc3.w + b3 : 0.f;

        *(float4*)(ob + ((long)(co + 0) << HW_SHIFT)) = r0;
        *(float4*)(ob + ((long)(co + 1) << HW_SHIFT)) = r1;
        *(float4*)(ob + ((long)(co + 2) << HW_SHIFT)) = r2;
        *(float4*)(ob + ((long)(co + 3) << HW_SHIFT)) = r3;
    }
}

extern "C" void kernel_launch(void* const* d_in, const int* in_sizes, int n_in,
                              void* d_out, int out_size, void* d_ws, size_t ws_size,
                              hipStream_t stream) {
    const float* x  = (const float*)d_in[0];   // [B, CIN, H, W] fp32
    const float* Wm = (const float*)d_in[1];   // [CIN, COUT] fp32
    const float* b  = (const float*)d_in[2];   // [COUT] fp32
    float* out = (float*)d_out;                // [B, COUT, H, W] fp32

    const long npos    = (long)in_sizes[0] / CIN;  // B*H*W = 2,097,152
    const int  nthread = (int)(npos / 4);          // 524,288
    const int  blocks  = nthread / 256;            // 2048

    spconv1x1_kernel<<<blocks, 256, 0, stream>>>(x, Wm, b, out);
}